// Round 15
// baseline (173.115 us; speedup 1.0000x reference)
//
#include <hip/hip_runtime.h>
#include <hip/hip_bf16.h>
#include <cstdint>

// Problem constants (fixed by setup_inputs)
#define B_    32
#define T_    4096
#define C_    256
#define BM    64     // time rows per block
#define DMAX  16     // max supported dilation (problem uses 4)
#define NROWS (BM + DMAX)

typedef __attribute__((ext_vector_type(8)))  short bf16x8;
typedef __attribute__((ext_vector_type(4)))  float f32x4;
typedef __attribute__((ext_vector_type(16))) float f32x16;
typedef __attribute__((ext_vector_type(4)))  short s16x4;

static __device__ __forceinline__ short f2bf(float f) {
  __hip_bfloat16 h = __float2bfloat16(f);
  union { __hip_bfloat16 h; short s; } u; u.h = h;
  return u.s;
}

static __device__ __forceinline__ float rcp_(float x) {
  return __builtin_amdgcn_rcpf(x);
}

// ---------------------------------------------------------------------------
// Prep: bf16 weight image for 32x32x16 A-fragments, direct per-lane loads:
//   wimg[ ((ks*16 + blk)*64 + lane)*8 + j ]   (shorts)
// ks = K-16 step (0..31), blk = f-block (0..7 value, 8..15 gate),
// lane = hi*32 + f5 (A-frag: row f = f5, k = hi*8 + j).
// A wave's fragment read = 64 lanes x 16B = 1KB contiguous (L2-coalesced).
// k = ks*16 + hi*8 + j: k<256 -> tap0 (x[t-d]), else tap1 (x[t]).
// ---------------------------------------------------------------------------
__global__ void prep_weights(const float* __restrict__ Wv, const float* __restrict__ Wg,
                             const float* __restrict__ bv, const float* __restrict__ bg,
                             short* __restrict__ wimg, float* __restrict__ bcat) {
  int id = blockIdx.x * 256 + threadIdx.x;   // 32*16*64*8 = 262144 total
  int j     = id & 7;
  int lane6 = (id >> 3) & 63;
  int blk   = (id >> 9) & 15;
  int ks    = id >> 13;
  int f5 = lane6 & 31, hi = lane6 >> 5;
  int k = ks * 16 + hi * 8 + j;
  int tap = k >> 8, kr = k & 255;
  int sel = blk >> 3;                 // 0=value, 1=gate
  int f = (blk & 7) * 32 + f5;
  const float* W = sel ? Wg : Wv;
  wimg[id] = f2bf(W[((size_t)tap * 256 + kr) * 256 + f]);
  if (id < 512) bcat[id] = (id < 256) ? bv[id] : bg[id - 256];
}

// ---------------------------------------------------------------------------
// Main (r9 skeleton, 32x32x16 MFMA): 512 threads = 8 waves, 1x8 N-partition:
// wave w owns value f [32w,+32) and gate f +256 (no weight duplication; per
// K=32: 4x 1KB weight loads + 8 MFMA + 4 ds_read_b128 — half the MFMA instrs
// of the 16x16 variant, same loads, acc=64). x staged ONCE per tile (LDS
// 40 KiB only); k-loop BARRIER-FREE with 2-slot weight prefetch ring.
// Transposed MFMA (weights in A-slot) -> float4 nt-stores.
// ---------------------------------------------------------------------------
__global__ __launch_bounds__(512, 4) void snail_main(
    const float* __restrict__ x, const short* __restrict__ wimg,
    const float* __restrict__ bcat, const int* __restrict__ dptr,
    float* __restrict__ out) {
  __shared__ __align__(16) short lx[NROWS * C_];   // 40 KiB, swizzled bf16 x-tile

  const int d = *dptr;
  // XCD-aware bijective swizzle (2048 blocks, 2048 % 8 == 0)
  const int bid = blockIdx.x;
  const int swz = (bid & 7) * 256 + (bid >> 3);
  const int t0 = (swz & 63) * BM;  // time tile
  const int b  = swz >> 6;         // batch

  const int tid  = threadIdx.x;
  const int lane = tid & 63;
  const int w    = tid >> 6;
  const int l31  = lane & 31;      // A/B fragment row/col
  const int hi   = lane >> 5;      // k-chunk selector
  const int hi16 = hi * 16;

  const float* xb = x + (size_t)b * T_ * C_;
  float* ob = out + (size_t)b * T_ * 512;

  // ---- stage x rows t0-d..t0+BM-1 into LDS (bf16, swizzled) once per tile;
  //      fuse the exact fp32 passthrough (full rows, contiguous).
  for (int i = tid; i < d * 64; i += 512) {          // prefix rows [0,d)
    int r = i >> 6, c4 = i & 63;
    int t = t0 - d + r;
    f32x4 v = (f32x4){0.f, 0.f, 0.f, 0.f};
    if (t >= 0) v = *(const f32x4*)(xb + (size_t)t * C_ + c4 * 4);
    s16x4 s;
    s.x = f2bf(v.x); s.y = f2bf(v.y); s.z = f2bf(v.z); s.w = f2bf(v.w);
    int byte = (r * 512 + c4 * 8) ^ ((r & 7) << 4);
    *(s16x4*)((char*)lx + byte) = s;
  }
#pragma unroll 4
  for (int ii = 0; ii < 8; ++ii) {                   // main rows [d, d+BM)
    int i = ii * 512 + tid;
    int rr = i >> 6, c4 = i & 63;
    int t = t0 + rr, r = rr + d;
    f32x4 v = *(const f32x4*)(xb + (size_t)t * C_ + c4 * 4);
    __builtin_nontemporal_store(v, (f32x4*)(ob + (size_t)t * 512 + C_ + c4 * 4));
    s16x4 s;
    s.x = f2bf(v.x); s.y = f2bf(v.y); s.z = f2bf(v.z); s.w = f2bf(v.w);
    int byte = (r * 512 + c4 * 8) ^ ((r & 7) << 4);
    *(s16x4*)((char*)lx + byte) = s;
  }
  __syncthreads();   // the ONLY barrier

  f32x16 accv[2], accg[2];
#pragma unroll
  for (int mi = 0; mi < 2; ++mi) {
    accv[mi] = (f32x16)(0.f);
    accg[mi] = (f32x16)(0.f);
  }

  // per-lane weight base (shorts): fragment (ks, blk) starts at (ks*16+blk)*512
  const short* wbase = wimg + lane * 8;

#define LOADW(WV, WG, KS) do {                                          \
    WV = *(const bf16x8*)(wbase + (size_t)((KS) * 16 + w) * 512);       \
    WG = *(const bf16x8*)(wbase + (size_t)((KS) * 16 + 8 + w) * 512);   \
  } while (0)

#define STEP(WV, WG, KS) do {                                           \
    bf16x8 af[2];                                                       \
    const int rofs_ = ((KS) >= 16) ? d : 0;                             \
    const int cb_ = ((KS) & 15) * 32 + hi16;                            \
    _Pragma("unroll")                                                   \
    for (int mi = 0; mi < 2; ++mi) {                                    \
      int r_ = 32 * mi + l31 + rofs_;                                   \
      af[mi] = *(const bf16x8*)((const char*)lx +                       \
               ((r_ * 512 + cb_) ^ ((r_ & 7) << 4)));                   \
    }                                                                   \
    _Pragma("unroll")                                                   \
    for (int mi = 0; mi < 2; ++mi) {                                    \
      accv[mi] = __builtin_amdgcn_mfma_f32_32x32x16_bf16(WV, af[mi], accv[mi], 0, 0, 0); \
      accg[mi] = __builtin_amdgcn_mfma_f32_32x32x16_bf16(WG, af[mi], accg[mi], 0, 0, 0); \
    }                                                                   \
  } while (0)

  bf16x8 av, ag, bv_, bg_;
  LOADW(av, ag, 0);
#pragma unroll 1
  for (int ks2 = 0; ks2 < 16; ++ks2) {
    LOADW(bv_, bg_, 2 * ks2 + 1);   // prefetch odd step
    STEP(av, ag, 2 * ks2);          // compute even step (loads in flight)
    if (ks2 < 15) LOADW(av, ag, 2 * ks2 + 2);  // prefetch next even
    STEP(bv_, bg_, 2 * ks2 + 1);    // compute odd step
  }
#undef LOADW
#undef STEP

  // ---- epilogue: out[t][f] = tanh(v+bv)*sigmoid(g+bg)
  //      = (e2v-1)*rcp((e2v+1)*(1+eng)), e2v=exp(2(v+bv)), eng=exp(-(g+bg))
  //      32x32 D^T layout: t = t0+32mi+l31 ; f = 32w + rg*8 + 4*hi + j,
  //      value acc element index = rg*4 + j (rg = 0..3).
#pragma unroll
  for (int mi = 0; mi < 2; ++mi) {
    int t = t0 + 32 * mi + l31;
#pragma unroll
    for (int rg = 0; rg < 4; ++rg) {
      int f0 = 32 * w + rg * 8 + 4 * hi;
      f32x4 bv4 = *(const f32x4*)(bcat + f0);
      f32x4 bg4 = *(const f32x4*)(bcat + 256 + f0);
      f32x4 res;
#pragma unroll
      for (int j = 0; j < 4; ++j) {
        float vv = accv[mi][rg * 4 + j];
        float gg = accg[mi][rg * 4 + j];
        float e2v = __expf(__builtin_fmaf(vv, 2.f, bv4[j] + bv4[j]));
        float eng = __expf(__builtin_fmaf(gg, -1.f, -bg4[j]));
        res[j] = (e2v - 1.f) * rcp_((e2v + 1.f) * (1.f + eng));
      }
      __builtin_nontemporal_store(res, (f32x4*)(ob + (size_t)t * 512 + f0));
    }
  }
}

extern "C" void kernel_launch(void* const* d_in, const int* in_sizes, int n_in,
                              void* d_out, int out_size, void* d_ws, size_t ws_size,
                              hipStream_t stream) {
  const float* x  = (const float*)d_in[0];
  const float* Wv = (const float*)d_in[1];
  const float* bv = (const float*)d_in[2];
  const float* Wg = (const float*)d_in[3];
  const float* bg = (const float*)d_in[4];
  const int* dil  = (const int*)d_in[5];
  float* out = (float*)d_out;

  short* wimg = (short*)d_ws;                          // 512 KiB weight image
  float* bcat = (float*)((char*)d_ws + 16 * 32768);    // 2 KiB biases

  prep_weights<<<1024, 256, 0, stream>>>(Wv, Wg, bv, bg, wimg, bcat);
  snail_main<<<B_ * (T_ / BM), 512, 0, stream>>>(x, wimg, bcat, dil, out);
}

// Round 16
// 122.286 us; speedup vs baseline: 1.4157x; 1.4157x over previous
//
#include <hip/hip_runtime.h>
#include <hip/hip_bf16.h>
#include <cstdint>

// Problem constants (fixed by setup_inputs)
#define B_    32
#define T_    4096
#define C_    256
#define BM    64     // time rows per tile
#define DMAX  8      // max supported dilation (problem uses 4)
#define NROWS (BM + DMAX)   // 72 LDS rows per buffer
#define NT    4      // tiles per block

typedef __attribute__((ext_vector_type(8))) short bf16x8;
typedef __attribute__((ext_vector_type(4))) float f32x4;
typedef __attribute__((ext_vector_type(4))) short s16x4;

static __device__ __forceinline__ short f2bf(float f) {
  __hip_bfloat16 h = __float2bfloat16(f);
  union { __hip_bfloat16 h; short s; } u; u.h = h;
  return u.s;
}

static __device__ __forceinline__ float rcp_(float x) {
  return __builtin_amdgcn_rcpf(x);
}

// ---------------------------------------------------------------------------
// Prep (r9 layout): bf16 weight image for direct per-lane fragment loads:
//   wimg[((nb*16 + ks)*256 + np)*32 + kk]   (shorts)
// nb = N-half, ks = k-step (K=32), np = local col (0..127 value, 128..255
// gate), kk = k within step. k = 32*ks + kk: k<256 -> tap0, else tap1.
// ---------------------------------------------------------------------------
__global__ void prep_weights(const float* __restrict__ Wv, const float* __restrict__ Wg,
                             const float* __restrict__ bv, const float* __restrict__ bg,
                             short* __restrict__ wimg, float* __restrict__ bcat) {
  int id = blockIdx.x * 256 + threadIdx.x;   // 2*16*256*32 = 262144 total
  int kk = id & 31;
  int np = (id >> 5) & 255;
  int ks = (id >> 13) & 15;
  int nb = id >> 17;
  int k = ks * 32 + kk, tap = k >> 8, kr = k & 255;
  int sel = np >> 7;
  int f = nb * 128 + (np & 127);
  const float* W = sel ? Wg : Wv;
  wimg[id] = f2bf(W[((size_t)tap * 256 + kr) * 256 + f]);
  if (id < 512) bcat[id] = (id < 256) ? bv[id] : bg[id - 256];
}

// ---------------------------------------------------------------------------
// Main: PRODUCER-CONSUMER wave specialization. 768 threads = 12 waves:
//   waves 0-7 (GEMM): exact r9 economics — 1x8 N-partition, per K-step
//     4x 1KB coalesced weight loads (ping-pong prefetch) + 16 MFMA, acc=64.
//   waves 8-11 (STAGE): continuously stream x for tile t+1 -> passthrough
//     nt-store + bf16 cvt + swizzled ds_write into the other LDS buffer.
// Block owns NT=4 consecutive tiles; ONE barrier per tile. EPI(t) overlaps
// stage(t+2) — memory phases are continuous instead of bursty (the 51%-HBM-
// duty fix). LDS 2x36KB; 12 waves/CU (3/SIMD at ~124 regs).
// ---------------------------------------------------------------------------
__global__ __launch_bounds__(768, 3) void snail_main(
    const float* __restrict__ x, const short* __restrict__ wimg,
    const float* __restrict__ bcat, const int* __restrict__ dptr,
    float* __restrict__ out) {
  __shared__ __align__(16) short lx[2][NROWS * C_];   // 2 x 36 KiB, swizzled

  const int d = *dptr;                    // problem: 4 (<= DMAX)
  const int bid = blockIdx.x;
  const int swz = (bid & 7) * 64 + (bid >> 3);   // 512 blocks, bijective
  const int b   = swz >> 4;               // batch
  const int t00 = (swz & 15) * (NT * BM); // first tile base

  const int tid  = threadIdx.x;
  const int lane = tid & 63;
  const int w    = tid >> 6;              // 0..11

  const float* xb = x + (size_t)b * T_ * C_;
  float* ob = out + (size_t)b * T_ * 512;

  const int nrows = BM + d;

  // ---- prologue: ALL 12 waves stage tile0 -> buf0 (+ its passthrough)
  for (int i = tid; i < nrows * 64; i += 768) {
    int r = i >> 6, c4 = i & 63;
    int t = t00 - d + r;
    f32x4 v = (f32x4){0.f, 0.f, 0.f, 0.f};
    if (t >= 0) v = *(const f32x4*)(xb + (size_t)t * C_ + c4 * 4);
    if (r >= d)
      __builtin_nontemporal_store(v, (f32x4*)(ob + (size_t)t * 512 + C_ + c4 * 4));
    s16x4 s;
    s.x = f2bf(v.x); s.y = f2bf(v.y); s.z = f2bf(v.z); s.w = f2bf(v.w);
    int byte = (r * 512 + c4 * 8) ^ ((r & 7) << 4);
    *(s16x4*)((char*)&lx[0][0] + byte) = s;
  }
  __syncthreads();

  if (w < 8) {
    // ================= GEMM role (waves 0-7) =================
    const int nb   = w >> 2;         // N-half owned by this wave
    const int wq   = w & 3;          // quarter within the half
    const int row15 = lane & 15;
    const int qw    = lane >> 4;

    // per-lane weight base: np = wq*32 + row15 (value), kk = qw*8
    const short* wl = wimg + (size_t)nb * 131072 + (wq * 32 + row15) * 32 + qw * 8;

    f32x4 accv[4][2], accg[4][2];

#define LOADW(D0, D1, D2, D3, KS) do {                                  \
    const short* wk_ = wl + (KS) * 8192;                                \
    D0 = *(const bf16x8*)(wk_);                                         \
    D1 = *(const bf16x8*)(wk_ + 512);                                   \
    D2 = *(const bf16x8*)(wk_ + 4096);                                  \
    D3 = *(const bf16x8*)(wk_ + 4608);                                  \
  } while (0)

#define STEP(BASE, B0, B1, G0, G1, KS) do {                             \
    bf16x8 af[4];                                                       \
    const int rofs_ = ((KS) >= 8) ? d : 0;                              \
    const int cb_ = ((KS) & 7) * 64 + qw * 16;                          \
    _Pragma("unroll")                                                   \
    for (int mi = 0; mi < 4; ++mi) {                                    \
      int r_ = 16 * mi + row15 + rofs_;                                 \
      af[mi] = *(const bf16x8*)((BASE) +                                \
               ((r_ * 512 + cb_) ^ ((r_ & 7) << 4)));                   \
    }                                                                   \
    _Pragma("unroll")                                                   \
    for (int mi = 0; mi < 4; ++mi) {                                    \
      accv[mi][0] = __builtin_amdgcn_mfma_f32_16x16x32_bf16(B0, af[mi], accv[mi][0], 0, 0, 0); \
      accv[mi][1] = __builtin_amdgcn_mfma_f32_16x16x32_bf16(B1, af[mi], accv[mi][1], 0, 0, 0); \
      accg[mi][0] = __builtin_amdgcn_mfma_f32_16x16x32_bf16(G0, af[mi], accg[mi][0], 0, 0, 0); \
      accg[mi][1] = __builtin_amdgcn_mfma_f32_16x16x32_bf16(G1, af[mi], accg[mi][1], 0, 0, 0); \
    }                                                                   \
  } while (0)

#pragma unroll 1
    for (int tt = 0; tt < NT; ++tt) {
      const int t0 = t00 + tt * BM;
      const char* base = (const char*)&lx[tt & 1][0];

#pragma unroll
      for (int mi = 0; mi < 4; ++mi)
#pragma unroll
        for (int ni = 0; ni < 2; ++ni) {
          accv[mi][ni] = (f32x4){0.f, 0.f, 0.f, 0.f};
          accg[mi][ni] = (f32x4){0.f, 0.f, 0.f, 0.f};
        }

      bf16x8 a0, a1, a2, a3, b0, b1, b2, b3;
      LOADW(a0, a1, a2, a3, 0);
#pragma unroll 1
      for (int ks2 = 0; ks2 < 8; ++ks2) {
        LOADW(b0, b1, b2, b3, 2 * ks2 + 1);   // prefetch odd step
        STEP(base, a0, a1, a2, a3, 2 * ks2);
        if (ks2 < 7) LOADW(a0, a1, a2, a3, 2 * ks2 + 2);
        STEP(base, b0, b1, b2, b3, 2 * ks2 + 1);
      }

      __syncthreads();   // done reading buf; stage waves done writing buf^1

      // ---- epilogue (overlaps stage of tile tt+2 on stage waves)
#pragma unroll
      for (int ni = 0; ni < 2; ++ni) {
        int f0 = nb * 128 + wq * 32 + 16 * ni + qw * 4;
        f32x4 bv4 = *(const f32x4*)(bcat + f0);
        f32x4 bg4 = *(const f32x4*)(bcat + 256 + f0);
        f32x4 bv2 = bv4 + bv4;     // 2*bias_v
        f32x4 bgn = -bg4;          // -bias_g
#pragma unroll
        for (int mi = 0; mi < 4; ++mi) {
          int t = t0 + 16 * mi + row15;
          f32x4 v = accv[mi][ni], g = accg[mi][ni];
          f32x4 res;
#pragma unroll
          for (int j = 0; j < 4; ++j) {
            float e2v = __expf(__builtin_fmaf(v[j], 2.f, bv2[j]));
            float eng = __expf(__builtin_fmaf(g[j], -1.f, bgn[j]));
            res[j] = (e2v - 1.f) * rcp_((e2v + 1.f) * (1.f + eng));
          }
          __builtin_nontemporal_store(res, (f32x4*)(ob + (size_t)t * 512 + f0));
        }
      }
    }
#undef LOADW
#undef STEP
  } else {
    // ================= STAGE role (waves 8-11) =================
    const int st = tid - 512;        // 0..255
#pragma unroll 1
    for (int tt = 0; tt < NT; ++tt) {
      if (tt < NT - 1) {
        const int tb = t00 + (tt + 1) * BM;   // next tile base
        char* dst = (char*)&lx[(tt + 1) & 1][0];
#pragma unroll 2
        for (int i = st; i < nrows * 64; i += 256) {
          int r = i >> 6, c4 = i & 63;
          int t = tb - d + r;
          f32x4 v = *(const f32x4*)(xb + (size_t)t * C_ + c4 * 4);  // t >= BM-d > 0
          if (r >= d)
            __builtin_nontemporal_store(v, (f32x4*)(ob + (size_t)t * 512 + C_ + c4 * 4));
          s16x4 s;
          s.x = f2bf(v.x); s.y = f2bf(v.y); s.z = f2bf(v.z); s.w = f2bf(v.w);
          int byte = (r * 512 + c4 * 8) ^ ((r & 7) << 4);
          *(s16x4*)(dst + byte) = s;
        }
      }
      __syncthreads();   // matches GEMM waves' per-tile barrier
    }
  }
}

extern "C" void kernel_launch(void* const* d_in, const int* in_sizes, int n_in,
                              void* d_out, int out_size, void* d_ws, size_t ws_size,
                              hipStream_t stream) {
  const float* x  = (const float*)d_in[0];
  const float* Wv = (const float*)d_in[1];
  const float* bv = (const float*)d_in[2];
  const float* Wg = (const float*)d_in[3];
  const float* bg = (const float*)d_in[4];
  const int* dil  = (const int*)d_in[5];
  float* out = (float*)d_out;

  short* wimg = (short*)d_ws;                          // 512 KiB weight image
  float* bcat = (float*)((char*)d_ws + 16 * 32768);    // 2 KiB biases

  prep_weights<<<1024, 256, 0, stream>>>(Wv, Wg, bv, bg, wimg, bcat);
  snail_main<<<B_ * (T_ / BM) / NT, 768, 0, stream>>>(x, wimg, bcat, dil, out);
}